// Round 21
// baseline (172.403 us; speedup 1.0000x reference)
//
#include <hip/hip_runtime.h>
#include <hip/hip_bf16.h>
#include <math.h>

#define NB 2
#define NL 2048
#define ND 512
#define NH 8
#define NDK 64
#define NROW (NB*NL)
#define HEADSZ (NB*NH*NL*NDK)
#define SEG_BIG ((size_t)NROW*ND)        // 2097152
#define SEG_SMALL ((size_t)ND*ND)        // 262144
#define TOT_W (8*SEG_SMALL)

typedef __attribute__((ext_vector_type(8))) short bf16x8;
typedef __attribute__((ext_vector_type(4))) float f32x4;

// static device scratch
__device__ __align__(16) short g_bfw[TOT_W];                     // bf16 weights, groups PRE-SWIZZLED (g^=row&7)
__device__ __align__(16) short g_bq_r[HEADSZ], g_bq_i[HEADSZ];   // Q * 0.125*log2e, bf16 [b,h,l,d]
__device__ __align__(16) short g_bk_r[HEADSZ], g_bk_i[HEADSZ];   // K bf16 [b,h,l,d], d-groups PRE-SWIZZLED (g^=l&7)
__device__ __align__(16) short g_bv_r[HEADSZ], g_bv_i[HEADSZ];   // V chunk-32 layout: [bh][c][r*8+p][8]
__device__ __align__(16) short g_bo_r[SEG_BIG], g_bo_i[SEG_BIG]; // attn out bf16, groups PRE-SWIZZLED (g^=row&7)
__device__ __align__(16) unsigned g_x[SEG_BIG];                  // post-FC + residual, packed bf16 (r|i<<16)
__device__ __align__(16) unsigned g_po[(size_t)2*16*NL*NDK];     // partial O packed bf16 [half][bh][q][d]
__device__ float g_pw[(size_t)2*16*NL];                          // partial ws [half][bh][q]

static __device__ __forceinline__ unsigned pack_bf2(float lo, float hi) {
    __hip_bfloat162 h = __float22bfloat162_rn(make_float2(lo, hi));
    unsigned u;
    __builtin_memcpy(&u, &h, 4);
    return u;
}
static __device__ __forceinline__ float bf_lo(unsigned u) {
    const unsigned v = u << 16;
    float f; __builtin_memcpy(&f, &v, 4);
    return f;
}
static __device__ __forceinline__ float bf_hi(unsigned u) {
    const unsigned v = u & 0xFFFF0000u;
    float f; __builtin_memcpy(&f, &v, 4);
    return f;
}
static __device__ __forceinline__ uint4 ld_cvt(const float* p) {
    const float4 a = *(const float4*)p;
    const float4 b = *(const float4*)(p + 4);
    uint4 o;
    o.x = pack_bf2(a.x, a.y); o.y = pack_bf2(a.z, a.w);
    o.z = pack_bf2(b.x, b.y); o.w = pack_bf2(b.z, b.w);
    return o;
}
static __device__ __forceinline__ bf16x8 negbf(bf16x8 v) {
    #pragma unroll
    for (int e = 0; e < 8; ++e) v[e] ^= (short)0x8000;
    return v;
}

struct GPtrs {
    const float* xr[3]; const float* xi[3];
    const float* rr; const float* ri;
};
struct WPtrs { const float* p[8]; };

// ---------------- fp32 -> bf16 pre-swizzled conversion (WEIGHTS ONLY) ----------------
__global__ __launch_bounds__(256)
void tobf(WPtrs wp)
{
    const size_t i = ((size_t)blockIdx.x*256 + threadIdx.x) * 8;
    if (i >= TOT_W) return;
    const int seg = (int)(i / SEG_SMALL);
    const size_t off = i % SEG_SMALL;
    const uint4 v = ld_cvt(wp.p[seg] + off);
    const int r7 = (int)(off >> 9) & 7;
    const int g  = (int)(off >> 3) & 7;
    const size_t dst = (off & ~(size_t)0x38) | ((size_t)(g ^ r7) << 3);
    *(uint4*)(g_bfw + (size_t)seg*SEG_SMALL + dst) = v;
}

// ---------------- bf16 MFMA complex GEMM, 64x64 tile (R18 form) ----------------
template<int MODE>
__global__ __launch_bounds__(256, 2)
void bgemm(GPtrs gp)
{
    __shared__ __align__(16) short sAB[16384];   // [Ar|Ai|Br|Bi] 4096 shorts each

    const int bm = blockIdx.x, bn = blockIdx.y;
    const int which = (MODE == 0) ? blockIdx.z : 3;
    const int tx = threadIdx.x;
    const int wave = tx >> 6, lane = tx & 63;
    const int l15 = lane & 15, l4 = lane >> 4;

    const float* Xr = nullptr;
    const float* Xi = nullptr;
    if constexpr (MODE == 0) { Xr = gp.xr[which]; Xi = gp.xi[which]; }
    const short* Wr = g_bfw + (size_t)(2*which)*SEG_SMALL;
    const short* Wi = g_bfw + (size_t)(2*which+1)*SEG_SMALL;

    const int t0r = tx >> 3;      // A staging row 0..31 (and +32)
    const int t0g = tx & 7;       // 8-elem group

    f32x4 Cr[4] = {}, Ci[4] = {};

    for (int kk = 0; kk < ND; kk += 64) {
        uint4 va0, va1, va2, va3;
        if constexpr (MODE == 0) {
            const size_t a0 = (size_t)(bm*64 + t0r)*ND + kk + t0g*8;
            const size_t a1 = a0 + (size_t)32*ND;
            va0 = ld_cvt(Xr + a0); va1 = ld_cvt(Xi + a0);
            va2 = ld_cvt(Xr + a1); va3 = ld_cvt(Xi + a1);
        }
        if constexpr (MODE == 0) {
            #pragma unroll
            for (int i_ = 0; i_ < 4; ++i_) {
                const int within = (i_ & 1)*256 + tx;       // 0..511
                const short* plane = (i_ >> 1) ? Wi : Wr;
                __builtin_amdgcn_global_load_lds(
                    (const __attribute__((address_space(1))) void*)
                        (plane + (size_t)(bn*64 + (within >> 3))*ND + kk + (within & 7)*8),
                    (__attribute__((address_space(3))) void*)
                        &sAB[8192 + (i_ >> 1)*4096 + within*8], 16, 0, 0);
            }
        } else {
            #pragma unroll
            for (int i_ = 0; i_ < 8; ++i_) {
                const int within = (i_ & 1)*256 + tx;       // 0..511
                const int pl = i_ >> 1;                     // 0=Ar 1=Ai 2=Br 3=Bi
                const short* plane = (pl == 0) ? g_bo_r : (pl == 1) ? g_bo_i : (pl == 2) ? Wr : Wi;
                const int row0 = (pl < 2) ? bm*64 : bn*64;
                __builtin_amdgcn_global_load_lds(
                    (const __attribute__((address_space(1))) void*)
                        (plane + (size_t)(row0 + (within >> 3))*ND + kk + (within & 7)*8),
                    (__attribute__((address_space(3))) void*)
                        &sAB[pl*4096 + within*8], 16, 0, 0);
            }
        }
        if constexpr (MODE == 0) {
            const int g0 = (t0g ^ (t0r & 7)) << 3;
            const int g1 = (t0g ^ ((t0r + 32) & 7)) << 3;
            *(uint4*)&sAB[t0r*64 + g0]               = va0;
            *(uint4*)&sAB[4096 + t0r*64 + g0]        = va1;
            *(uint4*)&sAB[(t0r+32)*64 + g1]          = va2;
            *(uint4*)&sAB[4096 + (t0r+32)*64 + g1]   = va3;
        }
        asm volatile("s_waitcnt vmcnt(0)" ::: "memory");
        __syncthreads();

        #pragma unroll
        for (int ks = 0; ks < 2; ++ks) {
            const int arow = 16*wave + l15;
            const int ag = ((ks*4 + l4) ^ (arow & 7)) << 3;
            const bf16x8 aAr = *(const bf16x8*)&sAB[arow*64 + ag];
            const bf16x8 aAi = *(const bf16x8*)&sAB[4096 + arow*64 + ag];
            const bf16x8 aAn = negbf(aAi);
            #pragma unroll
            for (int nt = 0; nt < 4; ++nt) {
                const int brow = nt*16 + l15;
                const int bg = ((ks*4 + l4) ^ (brow & 7)) << 3;
                const bf16x8 bBr = *(const bf16x8*)&sAB[8192  + brow*64 + bg];
                const bf16x8 bBi = *(const bf16x8*)&sAB[12288 + brow*64 + bg];
                Cr[nt] = __builtin_amdgcn_mfma_f32_16x16x32_bf16(aAr, bBr, Cr[nt], 0, 0, 0);
                Cr[nt] = __builtin_amdgcn_mfma_f32_16x16x32_bf16(aAn, bBi, Cr[nt], 0, 0, 0);
                Ci[nt] = __builtin_amdgcn_mfma_f32_16x16x32_bf16(aAr, bBi, Ci[nt], 0, 0, 0);
                Ci[nt] = __builtin_amdgcn_mfma_f32_16x16x32_bf16(aAi, bBr, Ci[nt], 0, 0, 0);
            }
        }
        __syncthreads();
    }

    // ---- epilogues ----
    const int m0 = bm*64 + 16*wave + 4*l4;    // 4 consecutive m in acc regs
    if constexpr (MODE == 0) {
        if (which == 2) {
            // V chunk-32 layout: element (d, l) -> [bh][c=l>>5][unit r*8+p][e=l&7]
            const int bb = m0 >> 11, ll = m0 & (NL-1);
            const int c = ll >> 5, lgrp = (ll >> 3) & 3, e = ll & 7;
            #pragma unroll
            for (int nt = 0; nt < 4; ++nt) {
                const int d = nt*16 + l15;
                const int r = d & 31, dpart = d >> 5;
                const int p = (4*dpart + lgrp) ^ (r & 7);
                const size_t off = (size_t)(bb*NH + bn)*(NL*NDK) + (size_t)c*2048 + (r*8 + p)*8 + e;
                *(uint2*)(g_bv_r + off) = make_uint2(pack_bf2(Cr[nt][0], Cr[nt][1]),
                                                     pack_bf2(Cr[nt][2], Cr[nt][3]));
                *(uint2*)(g_bv_i + off) = make_uint2(pack_bf2(Ci[nt][0], Ci[nt][1]),
                                                     pack_bf2(Ci[nt][2], Ci[nt][3]));
            }
        } else {
            // Q scale folds 1/sqrt(DK) AND log2(e) (softmax exp2 domain)
            const float s = (which == 0) ? 0.18033688f : 1.0f;
            short* Pr = (which == 0) ? g_bq_r : g_bk_r;
            short* Pi = (which == 0) ? g_bq_i : g_bk_i;
            #pragma unroll
            for (int r = 0; r < 4; ++r) {
                const int m = m0 + r;
                const int bb = m >> 11, ll = m & (NL-1);
                const size_t base = ((size_t)(bb*NH + bn)*NL + ll)*NDK;
                #pragma unroll
                for (int nt = 0; nt < 4; ++nt) {
                    int col = nt*16 + l15;
                    if (which == 1)   // pre-swizzle K d-groups for linear DMA staging
                        col = (col & 7) | ((((col >> 3) ^ (ll & 7))) << 3);
                    const unsigned pk = pack_bf2(Cr[nt][r]*s, Ci[nt][r]*s);
                    Pr[base + col] = (short)(pk & 0xFFFFu);
                    Pi[base + col] = (short)(pk >> 16);
                }
            }
        }
    } else {
        const float* Rr = gp.rr;
        const float* Ri = gp.ri;
        #pragma unroll
        for (int r = 0; r < 4; ++r) {
            const int m = m0 + r;
            const size_t base = (size_t)m*ND + bn*64;
            #pragma unroll
            for (int nt = 0; nt < 4; ++nt) {
                const size_t idx = base + nt*16 + l15;
                g_x[idx] = pack_bf2(Cr[nt][r] + Rr[idx], Ci[nt][r] + Ri[idx]);
            }
        }
    }
}

// ---------------- MFMA flash attention: 2 chunks per barrier, 4-deep KV ring ----------------
// LDS 40KB: KV ring 4x8KB + coef 8KB -> 4 blocks/CU. Per iteration: stage
// chunks t+2,t+3 (disjoint ring slots), compute chunk t then t+1 (each with
// wave-local lgkm drain), ONE vmcnt(0)+barrier. Halves barrier count; 8 DMA
// loads in flight. |s| already in log2e units (Q pre-scaled).
__global__ __launch_bounds__(256, 4)
void cattn()
{
    __shared__ __align__(16) short sKV[4][8192];              // ring [buf][Kr|Ki|Vr|Vi]
    __shared__ __align__(16) short sCr[64][32], sCi[64][32];  // coeffs [q][k32] (own-wave region)

    const int nb = blockIdx.x;
    const int xcd = nb & 7, rest = nb >> 3;        // rest 0..127
    const int bh = xcd*2 + (rest >> 6);
    const int within = rest & 63;
    const int q0 = (within >> 1) * 64;
    const int half = within & 1;

    const int tx = threadIdx.x;
    const int wave = tx >> 6, lane = tx & 63;
    const int l15 = lane & 15, l4 = lane >> 4;

    const short* Kr = g_bk_r + (size_t)bh*NL*NDK;
    const short* Ki = g_bk_i + (size_t)bh*NL*NDK;
    const short* Vr = g_bv_r + (size_t)bh*NL*NDK;
    const short* Vi = g_bv_i + (size_t)bh*NL*NDK;

    bf16x8 aQr[2], aQi[2], aQn[2];
    {
        const size_t qb = ((size_t)bh*NL + q0 + 16*wave + l15)*NDK + 8*l4;
        aQr[0] = *(const bf16x8*)(g_bq_r + qb);
        aQr[1] = *(const bf16x8*)(g_bq_r + qb + 32);
        aQi[0] = *(const bf16x8*)(g_bq_i + qb);
        aQi[1] = *(const bf16x8*)(g_bq_i + qb + 32);
        aQn[0] = negbf(aQi[0]); aQn[1] = negbf(aQi[1]);
    }

    f32x4 Or[4] = {}, Oi[4] = {};
    float ws[4] = {0.f, 0.f, 0.f, 0.f};

    const short* kvplane = (wave == 0) ? Kr : (wave == 1) ? Ki : (wave == 2) ? Vr : Vi;
    const int pbase = wave * 2048;

    #define STAGE_KV(CHUNK, BUF) do {                                         \
        _Pragma("unroll")                                                     \
        for (int i_ = 0; i_ < 4; ++i_) {                                      \
            const int u_ = i_*64 + lane;                                      \
            __builtin_amdgcn_global_load_lds(                                 \
                (const __attribute__((address_space(1))) void*)               \
                    (kvplane + (size_t)(CHUNK)*2048 + (size_t)u_*8),          \
                (__attribute__((address_space(3))) void*)                     \
                    &sKV[BUF][pbase + u_*8], 16, 0, 0);                       \
        }                                                                     \
    } while (0)

    const float SHIFT = -5.770780163f;     // -4 * log2(e)

    // V fragment LDS offsets (static per lane)
    int voff[4];
    #pragma unroll
    for (int tt = 0; tt < 4; ++tt) {
        const int r = (tt*16 + l15) & 31, dpart = tt >> 1;
        const int p = (4*dpart + l4) ^ (r & 7);
        voff[tt] = r*64 + p*8;
    }

    // one chunk's compute from ring slot BUF
    #define CHUNK_COMPUTE(BUF) do {                                           \
        _Pragma("unroll")                                                     \
        for (int tt = 0; tt < 2; ++tt) {                                      \
            const int row = tt*16 + l15;                                      \
            const int swb = row & 7;                                          \
            f32x4 Sr = {}, Si = {};                                           \
            __builtin_amdgcn_s_setprio(1);                                    \
            _Pragma("unroll")                                                 \
            for (int c = 0; c < 2; ++c) {                                     \
                const int off = (((c*4 + l4) ^ swb) << 3);                    \
                const bf16x8 bKr = *(const bf16x8*)&sKV[BUF][row*64 + off];   \
                const bf16x8 bKi = *(const bf16x8*)&sKV[BUF][2048 + row*64 + off]; \
                Sr = __builtin_amdgcn_mfma_f32_16x16x32_bf16(aQr[c], bKr, Sr, 0, 0, 0); \
                Sr = __builtin_amdgcn_mfma_f32_16x16x32_bf16(aQn[c], bKi, Sr, 0, 0, 0); \
                Si = __builtin_amdgcn_mfma_f32_16x16x32_bf16(aQr[c], bKi, Si, 0, 0, 0); \
                Si = __builtin_amdgcn_mfma_f32_16x16x32_bf16(aQi[c], bKr, Si, 0, 0, 0); \
            }                                                                 \
            __builtin_amdgcn_s_setprio(0);                                    \
            const int kgrp = row >> 3;                                        \
            _Pragma("unroll")                                                 \
            for (int r = 0; r < 4; ++r) {                                     \
                const int qrow = 16*wave + 4*l4 + r;                          \
                const float s2 = fmaxf(fmaf(Sr[r], Sr[r], Si[r]*Si[r]), 1e-30f); \
                const float irs = __builtin_amdgcn_rsqf(s2);                  \
                const float mag = s2 * irs;                                   \
                const float w = exp2f(mag + SHIFT);                           \
                const float sc = w * irs;                                     \
                ws[r] += w;                                                   \
                const int col = (row & 7) | ((kgrp ^ ((qrow >> 2) & 3)) << 3); \
                const unsigned pk = pack_bf2(Sr[r]*sc, Si[r]*sc);             \
                sCr[qrow][col] = (short)(pk & 0xFFFFu);                       \
                sCi[qrow][col] = (short)(pk >> 16);                           \
            }                                                                 \
        }                                                                     \
        bf16x8 vfr0 = *(const bf16x8*)&sKV[BUF][4096 + voff[0]];              \
        bf16x8 vfi0 = *(const bf16x8*)&sKV[BUF][6144 + voff[0]];              \
        bf16x8 vfr1 = *(const bf16x8*)&sKV[BUF][4096 + voff[1]];              \
        bf16x8 vfi1 = *(const bf16x8*)&sKV[BUF][6144 + voff[1]];              \
        bf16x8 vfr2 = *(const bf16x8*)&sKV[BUF][4096 + voff[2]];              \
        bf16x8 vfi2 = *(const bf16x8*)&sKV[BUF][6144 + voff[2]];              \
        bf16x8 vfr3 = *(const bf16x8*)&sKV[BUF][4096 + voff[3]];              \
        bf16x8 vfi3 = *(const bf16x8*)&sKV[BUF][6144 + voff[3]];              \
        asm volatile("s_waitcnt lgkmcnt(0)" ::: "memory");                    \
        __builtin_amdgcn_sched_barrier(0);                                    \
        bf16x8 aCr, aCi, aCn;                                                 \
        {                                                                     \
            const int qrow = 16*wave + l15;                                   \
            const int off = (l4 ^ ((qrow >> 2) & 3)) << 3;                    \
            aCr = *(const bf16x8*)&sCr[qrow][off];                            \
            aCi = *(const bf16x8*)&sCi[qrow][off];                            \
            aCn = negbf(aCi);                                                 \
        }                                                                     \
        __builtin_amdgcn_s_setprio(1);                                        \
        Or[0] = __builtin_amdgcn_mfma_f32_16x16x32_bf16(aCr, vfr0, Or[0], 0, 0, 0); \
        Or[0] = __builtin_amdgcn_mfma_f32_16x16x32_bf16(aCn, vfi0, Or[0], 0, 0, 0); \
        Oi[0] = __builtin_amdgcn_mfma_f32_16x16x32_bf16(aCr, vfi0, Oi[0], 0, 0, 0); \
        Oi[0] = __builtin_amdgcn_mfma_f32_16x16x32_bf16(aCi, vfr0, Oi[0], 0, 0, 0); \
        Or[1] = __builtin_amdgcn_mfma_f32_16x16x32_bf16(aCr, vfr1, Or[1], 0, 0, 0); \
        Or[1] = __builtin_amdgcn_mfma_f32_16x16x32_bf16(aCn, vfi1, Or[1], 0, 0, 0); \
        Oi[1] = __builtin_amdgcn_mfma_f32_16x16x32_bf16(aCr, vfi1, Oi[1], 0, 0, 0); \
        Oi[1] = __builtin_amdgcn_mfma_f32_16x16x32_bf16(aCi, vfr1, Oi[1], 0, 0, 0); \
        Or[2] = __builtin_amdgcn_mfma_f32_16x16x32_bf16(aCr, vfr2, Or[2], 0, 0, 0); \
        Or[2] = __builtin_amdgcn_mfma_f32_16x16x32_bf16(aCn, vfi2, Or[2], 0, 0, 0); \
        Oi[2] = __builtin_amdgcn_mfma_f32_16x16x32_bf16(aCr, vfi2, Oi[2], 0, 0, 0); \
        Oi[2] = __builtin_amdgcn_mfma_f32_16x16x32_bf16(aCi, vfr2, Oi[2], 0, 0, 0); \
        Or[3] = __builtin_amdgcn_mfma_f32_16x16x32_bf16(aCr, vfr3, Or[3], 0, 0, 0); \
        Or[3] = __builtin_amdgcn_mfma_f32_16x16x32_bf16(aCn, vfi3, Or[3], 0, 0, 0); \
        Oi[3] = __builtin_amdgcn_mfma_f32_16x16x32_bf16(aCr, vfi3, Oi[3], 0, 0, 0); \
        Oi[3] = __builtin_amdgcn_mfma_f32_16x16x32_bf16(aCi, vfr3, Oi[3], 0, 0, 0); \
        __builtin_amdgcn_s_setprio(0);                                        \
    } while (0)

    const int cbase = half * 32;
    // prologue: stage chunks 0,1 into ring slots 0,1
    STAGE_KV(cbase + 0, 0);
    STAGE_KV(cbase + 1, 1);
    asm volatile("s_waitcnt vmcnt(0)" ::: "memory");
    __syncthreads();

    for (int t = 0; t < 32; t += 2) {
        if (t + 2 < 32) STAGE_KV(cbase + t + 2, (t + 2) & 3);
        if (t + 3 < 32) STAGE_KV(cbase + t + 3, (t + 3) & 3);
        CHUNK_COMPUTE(t & 3);
        CHUNK_COMPUTE((t + 1) & 3);
        asm volatile("s_waitcnt vmcnt(0)" ::: "memory");   // staged chunks landed
        __syncthreads();                                    // block-wide ready
    }

    // ---- epilogue: reduce ws over 16-lane group; write packed bf16 partials ----
    #pragma unroll
    for (int r = 0; r < 4; ++r) {
        #pragma unroll
        for (int off = 8; off; off >>= 1) ws[r] += __shfl_xor(ws[r], off);
    }
    const size_t pb = (size_t)(half*16 + bh)*NL;
    if (l15 == 0) {
        #pragma unroll
        for (int r = 0; r < 4; ++r)
            g_pw[pb + q0 + 16*wave + 4*l4 + r] = ws[r];
    }
    #pragma unroll
    for (int tt = 0; tt < 4; ++tt) {
        const int d = tt*16 + l15;
        #pragma unroll
        for (int r = 0; r < 4; ++r) {
            const int q = q0 + 16*wave + 4*l4 + r;
            g_po[(pb + q)*NDK + d] = pack_bf2(Or[tt][r], Oi[tt][r]);
        }
    }
    #undef CHUNK_COMPUTE
    #undef STAGE_KV
}

// ---------------- combine halves, normalize, emit bf16 PRE-SWIZZLED ----------------
__global__ __launch_bounds__(256)
void comb()
{
    const size_t t4 = ((size_t)blockIdx.x*256 + threadIdx.x) * 4;  // 2^21 elems total
    const int d = (int)(t4 & 63);
    const int q = (int)((t4 >> 6) & (NL-1));
    const int bh = (int)(t4 >> 17);
    const size_t p = ((size_t)bh*NL + q)*NDK + d;
    const uint4 a = *(const uint4*)&g_po[p];
    const uint4 c = *(const uint4*)&g_po[(size_t)16*NL*NDK + p];
    const float w = g_pw[(size_t)bh*NL + q] + g_pw[(size_t)(16 + bh)*NL + q];
    const float inv = 1.0f / w;
    float fr[4], fi[4];
    fr[0] = (bf_lo(a.x) + bf_lo(c.x))*inv; fi[0] = (bf_hi(a.x) + bf_hi(c.x))*inv;
    fr[1] = (bf_lo(a.y) + bf_lo(c.y))*inv; fi[1] = (bf_hi(a.y) + bf_hi(c.y))*inv;
    fr[2] = (bf_lo(a.z) + bf_lo(c.z))*inv; fi[2] = (bf_hi(a.z) + bf_hi(c.z))*inv;
    fr[3] = (bf_lo(a.w) + bf_lo(c.w))*inv; fi[3] = (bf_hi(a.w) + bf_hi(c.w))*inv;
    const int b = bh >> 3, h = bh & 7;
    const int dsw = ((((d >> 3) ^ (q & 7))) << 3) | (d & 7);   // pre-swizzle group
    const size_t o = ((size_t)b*NL + q)*ND + h*NDK + dsw;
    *(uint2*)(g_bo_r + o) = make_uint2(pack_bf2(fr[0], fr[1]), pack_bf2(fr[2], fr[3]));
    *(uint2*)(g_bo_i + o) = make_uint2(pack_bf2(fi[0], fi[1]), pack_bf2(fi[2], fi[3]));
}

// ---------------- covariance-whitening complex LayerNorm (packed g_x) ----------------
__global__ __launch_bounds__(256)
void cvln(const float* __restrict__ ln_w, const float* __restrict__ lnb_r,
          const float* __restrict__ lnb_i, float2* __restrict__ out)
{
    __shared__ float red[4][5];
    const int row = blockIdx.x, tx = threadIdx.x;
    const unsigned* xp = g_x + (size_t)row*ND;
    const unsigned u0 = xp[tx], u1 = xp[tx + 256];
    const float a0 = bf_lo(u0), a1 = bf_lo(u1);
    const float b0 = bf_hi(u0), b1 = bf_hi(u1);
    float s_r = a0 + a1, s_i = b0 + b1;
    float srr = a0*a0 + a1*a1, sii = b0*b0 + b1*b1, sri = a0*b0 + a1*b1;
    #pragma unroll
    for (int off = 32; off; off >>= 1) {
        s_r += __shfl_xor(s_r, off);  s_i += __shfl_xor(s_i, off);
        srr += __shfl_xor(srr, off);  sii += __shfl_xor(sii, off);
        sri += __shfl_xor(sri, off);
    }
    const int wave = tx >> 6, lane = tx & 63;
    if (lane == 0) { red[wave][0]=s_r; red[wave][1]=s_i; red[wave][2]=srr; red[wave][3]=sii; red[wave][4]=sri; }
    __syncthreads();
    s_r = red[0][0]+red[1][0]+red[2][0]+red[3][0];
    s_i = red[0][1]+red[1][1]+red[2][1]+red[3][1];
    srr = red[0][2]+red[1][2]+red[2][2]+red[3][2];
    sii = red[0][3]+red[1][3]+red[2][3]+red[3][3];
    sri = red[0][4]+red[1][4]+red[2][4]+red[3][4];

    const float invD = 1.0f/ND;
    const float mr = s_r*invD, mi = s_i*invD;
    const float vrr = srr*invD - mr*mr + 1e-6f;
    const float vii = sii*invD - mi*mi + 1e-6f;
    const float vri = sri*invD - mr*mi;
    const float s  = sqrtf(vrr*vii - vri*vri);
    const float t  = sqrtf(vrr + vii + 2.0f*s);
    const float inv = 1.0f/(s*t);
    const float rrr = (vii + s)*inv, rii = (vrr + s)*inv, rri = -vri*inv;

    #pragma unroll
    for (int p = 0; p < 2; ++p) {
        const int d = tx + p*256;
        const float cxr = (p ? a1 : a0) - mr;
        const float cxi = (p ? b1 : b0) - mi;
        const float yr = rrr*cxr + rri*cxi;
        const float yi = rri*cxr + rii*cxi;
        const float w00 = ln_w[d], w01 = ln_w[512 + d];
        const float w10 = ln_w[1024 + d], w11 = ln_w[1536 + d];
        out[(size_t)row*ND + d] = make_float2(w00*yr + w01*yi + lnb_r[d],
                                              w10*yr + w11*yi + lnb_i[d]);
    }
}

extern "C" void kernel_launch(void* const* d_in, const int* in_sizes, int n_in,
                              void* d_out, int out_size, void* d_ws, size_t ws_size,
                              hipStream_t stream)
{
    (void)in_sizes; (void)n_in; (void)d_ws; (void)ws_size; (void)out_size;
    const float* ln_w = (const float*)d_in[14];
    const float* lnbr = (const float*)d_in[15];
    const float* lnbi = (const float*)d_in[16];

    GPtrs gp;
    gp.xr[0] = (const float*)d_in[0];  gp.xi[0] = (const float*)d_in[1];
    gp.xr[1] = (const float*)d_in[2];  gp.xi[1] = (const float*)d_in[3];
    gp.xr[2] = (const float*)d_in[4];  gp.xi[2] = (const float*)d_in[5];
    gp.rr = (const float*)d_in[0];     gp.ri = (const float*)d_in[1];

    WPtrs wp;
    for (int j = 0; j < 8; ++j) wp.p[j] = (const float*)d_in[6 + j];

    const int wcvt_blocks = (int)((TOT_W/8 + 255)/256);
    tobf<<<wcvt_blocks, 256, 0, stream>>>(wp);
    bgemm<0><<<dim3(NROW/64, ND/64, 3), 256, 0, stream>>>(gp);
    cattn<<<1024, 256, 0, stream>>>();
    comb<<<2048, 256, 0, stream>>>();
    bgemm<1><<<dim3(NROW/64, ND/64), 256, 0, stream>>>(gp);
    cvln<<<NROW, 256, 0, stream>>>(ln_w, lnbr, lnbi, (float2*)d_out);
}

// Round 22
// 160.630 us; speedup vs baseline: 1.0733x; 1.0733x over previous
//
#include <hip/hip_runtime.h>
#include <hip/hip_bf16.h>
#include <math.h>

#define NB 2
#define NL 2048
#define ND 512
#define NH 8
#define NDK 64
#define NROW (NB*NL)
#define HEADSZ (NB*NH*NL*NDK)
#define SEG_BIG ((size_t)NROW*ND)        // 2097152
#define SEG_SMALL ((size_t)ND*ND)        // 262144
#define TOT_W (8*SEG_SMALL)

typedef __attribute__((ext_vector_type(8))) short bf16x8;
typedef __attribute__((ext_vector_type(4))) float f32x4;

// static device scratch
__device__ __align__(16) short g_bfw[TOT_W];                     // bf16 weights, groups PRE-SWIZZLED (g^=row&7)
__device__ __align__(16) short g_bq_r[HEADSZ], g_bq_i[HEADSZ];   // Q * 0.125*log2e, bf16 [b,h,l,d]
__device__ __align__(16) short g_bk_r[HEADSZ], g_bk_i[HEADSZ];   // K bf16 [b,h,l,d], d-groups PRE-SWIZZLED (g^=l&7)
__device__ __align__(16) short g_bv_r[HEADSZ], g_bv_i[HEADSZ];   // V chunk-32 layout: [bh][c][r*8+p][8]
__device__ __align__(16) short g_bo_r[SEG_BIG], g_bo_i[SEG_BIG]; // attn out bf16, groups PRE-SWIZZLED (g^=row&7)
__device__ __align__(16) unsigned g_x[SEG_BIG];                  // post-FC + residual, packed bf16 (r|i<<16)
__device__ __align__(16) unsigned g_po[(size_t)2*16*NL*NDK];     // partial O packed bf16 [half][bh][q][d]
__device__ float g_pw[(size_t)2*16*NL];                          // partial ws [half][bh][q]

static __device__ __forceinline__ unsigned pack_bf2(float lo, float hi) {
    __hip_bfloat162 h = __float22bfloat162_rn(make_float2(lo, hi));
    unsigned u;
    __builtin_memcpy(&u, &h, 4);
    return u;
}
static __device__ __forceinline__ float bf_lo(unsigned u) {
    const unsigned v = u << 16;
    float f; __builtin_memcpy(&f, &v, 4);
    return f;
}
static __device__ __forceinline__ float bf_hi(unsigned u) {
    const unsigned v = u & 0xFFFF0000u;
    float f; __builtin_memcpy(&f, &v, 4);
    return f;
}
static __device__ __forceinline__ uint4 ld_cvt(const float* p) {
    const float4 a = *(const float4*)p;
    const float4 b = *(const float4*)(p + 4);
    uint4 o;
    o.x = pack_bf2(a.x, a.y); o.y = pack_bf2(a.z, a.w);
    o.z = pack_bf2(b.x, b.y); o.w = pack_bf2(b.z, b.w);
    return o;
}
static __device__ __forceinline__ bf16x8 negbf(bf16x8 v) {
    #pragma unroll
    for (int e = 0; e < 8; ++e) v[e] ^= (short)0x8000;
    return v;
}

struct GPtrs {
    const float* xr[3]; const float* xi[3];
    const float* rr; const float* ri;
};
struct WPtrs { const float* p[8]; };

// ---------------- fp32 -> bf16 pre-swizzled conversion (WEIGHTS ONLY) ----------------
__global__ __launch_bounds__(256)
void tobf(WPtrs wp)
{
    const size_t i = ((size_t)blockIdx.x*256 + threadIdx.x) * 8;
    if (i >= TOT_W) return;
    const int seg = (int)(i / SEG_SMALL);
    const size_t off = i % SEG_SMALL;
    const uint4 v = ld_cvt(wp.p[seg] + off);
    const int r7 = (int)(off >> 9) & 7;
    const int g  = (int)(off >> 3) & 7;
    const size_t dst = (off & ~(size_t)0x38) | ((size_t)(g ^ r7) << 3);
    *(uint4*)(g_bfw + (size_t)seg*SEG_SMALL + dst) = v;
}

// ---------------- bf16 MFMA complex GEMM, 64x64 tile ----------------
// MODE 0: hybrid — A (activation, read-once) reg-staged fp32->cvt->swizzled
//         ds_write; B (weights) DMA from pre-swizzled g_bfw.
// MODE 1: full DMA — A = g_bo (pre-swizzled bf16 from comb), B = fc weights.
//         Epilogue -> g_x packed bf16 with residual added.
template<int MODE>
__global__ __launch_bounds__(256, 2)
void bgemm(GPtrs gp)
{
    __shared__ __align__(16) short sAB[16384];   // [Ar|Ai|Br|Bi] 4096 shorts each

    const int bm = blockIdx.x, bn = blockIdx.y;
    const int which = (MODE == 0) ? blockIdx.z : 3;
    const int tx = threadIdx.x;
    const int wave = tx >> 6, lane = tx & 63;
    const int l15 = lane & 15, l4 = lane >> 4;

    const float* Xr = nullptr;
    const float* Xi = nullptr;
    if constexpr (MODE == 0) { Xr = gp.xr[which]; Xi = gp.xi[which]; }
    const short* Wr = g_bfw + (size_t)(2*which)*SEG_SMALL;
    const short* Wi = g_bfw + (size_t)(2*which+1)*SEG_SMALL;

    const int t0r = tx >> 3;      // A staging row 0..31 (and +32)
    const int t0g = tx & 7;       // 8-elem group

    f32x4 Cr[4] = {}, Ci[4] = {};

    for (int kk = 0; kk < ND; kk += 64) {
        uint4 va0, va1, va2, va3;
        if constexpr (MODE == 0) {
            const size_t a0 = (size_t)(bm*64 + t0r)*ND + kk + t0g*8;
            const size_t a1 = a0 + (size_t)32*ND;
            va0 = ld_cvt(Xr + a0); va1 = ld_cvt(Xi + a0);
            va2 = ld_cvt(Xr + a1); va3 = ld_cvt(Xi + a1);
        }
        if constexpr (MODE == 0) {
            #pragma unroll
            for (int i_ = 0; i_ < 4; ++i_) {
                const int within = (i_ & 1)*256 + tx;       // 0..511
                const short* plane = (i_ >> 1) ? Wi : Wr;
                __builtin_amdgcn_global_load_lds(
                    (const __attribute__((address_space(1))) void*)
                        (plane + (size_t)(bn*64 + (within >> 3))*ND + kk + (within & 7)*8),
                    (__attribute__((address_space(3))) void*)
                        &sAB[8192 + (i_ >> 1)*4096 + within*8], 16, 0, 0);
            }
        } else {
            #pragma unroll
            for (int i_ = 0; i_ < 8; ++i_) {
                const int within = (i_ & 1)*256 + tx;       // 0..511
                const int pl = i_ >> 1;                     // 0=Ar 1=Ai 2=Br 3=Bi
                const short* plane = (pl == 0) ? g_bo_r : (pl == 1) ? g_bo_i : (pl == 2) ? Wr : Wi;
                const int row0 = (pl < 2) ? bm*64 : bn*64;
                __builtin_amdgcn_global_load_lds(
                    (const __attribute__((address_space(1))) void*)
                        (plane + (size_t)(row0 + (within >> 3))*ND + kk + (within & 7)*8),
                    (__attribute__((address_space(3))) void*)
                        &sAB[pl*4096 + within*8], 16, 0, 0);
            }
        }
        if constexpr (MODE == 0) {
            const int g0 = (t0g ^ (t0r & 7)) << 3;
            const int g1 = (t0g ^ ((t0r + 32) & 7)) << 3;
            *(uint4*)&sAB[t0r*64 + g0]               = va0;
            *(uint4*)&sAB[4096 + t0r*64 + g0]        = va1;
            *(uint4*)&sAB[(t0r+32)*64 + g1]          = va2;
            *(uint4*)&sAB[4096 + (t0r+32)*64 + g1]   = va3;
        }
        asm volatile("s_waitcnt vmcnt(0)" ::: "memory");
        __syncthreads();

        #pragma unroll
        for (int ks = 0; ks < 2; ++ks) {
            const int arow = 16*wave + l15;
            const int ag = ((ks*4 + l4) ^ (arow & 7)) << 3;
            const bf16x8 aAr = *(const bf16x8*)&sAB[arow*64 + ag];
            const bf16x8 aAi = *(const bf16x8*)&sAB[4096 + arow*64 + ag];
            const bf16x8 aAn = negbf(aAi);
            #pragma unroll
            for (int nt = 0; nt < 4; ++nt) {
                const int brow = nt*16 + l15;
                const int bg = ((ks*4 + l4) ^ (brow & 7)) << 3;
                const bf16x8 bBr = *(const bf16x8*)&sAB[8192  + brow*64 + bg];
                const bf16x8 bBi = *(const bf16x8*)&sAB[12288 + brow*64 + bg];
                Cr[nt] = __builtin_amdgcn_mfma_f32_16x16x32_bf16(aAr, bBr, Cr[nt], 0, 0, 0);
                Cr[nt] = __builtin_amdgcn_mfma_f32_16x16x32_bf16(aAn, bBi, Cr[nt], 0, 0, 0);
                Ci[nt] = __builtin_amdgcn_mfma_f32_16x16x32_bf16(aAr, bBi, Ci[nt], 0, 0, 0);
                Ci[nt] = __builtin_amdgcn_mfma_f32_16x16x32_bf16(aAi, bBr, Ci[nt], 0, 0, 0);
            }
        }
        __syncthreads();
    }

    // ---- epilogues ----
    const int m0 = bm*64 + 16*wave + 4*l4;    // 4 consecutive m in acc regs
    if constexpr (MODE == 0) {
        if (which == 2) {
            // V chunk-32 layout: element (d, l) -> [bh][c=l>>5][unit r*8+p][e=l&7]
            const int bb = m0 >> 11, ll = m0 & (NL-1);
            const int c = ll >> 5, lgrp = (ll >> 3) & 3, e = ll & 7;
            #pragma unroll
            for (int nt = 0; nt < 4; ++nt) {
                const int d = nt*16 + l15;
                const int r = d & 31, dpart = d >> 5;
                const int p = (4*dpart + lgrp) ^ (r & 7);
                const size_t off = (size_t)(bb*NH + bn)*(NL*NDK) + (size_t)c*2048 + (r*8 + p)*8 + e;
                *(uint2*)(g_bv_r + off) = make_uint2(pack_bf2(Cr[nt][0], Cr[nt][1]),
                                                     pack_bf2(Cr[nt][2], Cr[nt][3]));
                *(uint2*)(g_bv_i + off) = make_uint2(pack_bf2(Ci[nt][0], Ci[nt][1]),
                                                     pack_bf2(Ci[nt][2], Ci[nt][3]));
            }
        } else {
            // Q scale folds 1/sqrt(DK) AND log2(e) (softmax runs in exp2 domain)
            const float s = (which == 0) ? 0.18033688f : 1.0f;
            short* Pr = (which == 0) ? g_bq_r : g_bk_r;
            short* Pi = (which == 0) ? g_bq_i : g_bk_i;
            #pragma unroll
            for (int r = 0; r < 4; ++r) {
                const int m = m0 + r;
                const int bb = m >> 11, ll = m & (NL-1);
                const size_t base = ((size_t)(bb*NH + bn)*NL + ll)*NDK;
                #pragma unroll
                for (int nt = 0; nt < 4; ++nt) {
                    int col = nt*16 + l15;
                    if (which == 1)   // pre-swizzle K d-groups for linear DMA staging
                        col = (col & 7) | ((((col >> 3) ^ (ll & 7))) << 3);
                    const unsigned pk = pack_bf2(Cr[nt][r]*s, Ci[nt][r]*s);
                    Pr[base + col] = (short)(pk & 0xFFFFu);
                    Pi[base + col] = (short)(pk >> 16);
                }
            }
        }
    } else {
        const float* Rr = gp.rr;
        const float* Ri = gp.ri;
        #pragma unroll
        for (int r = 0; r < 4; ++r) {
            const int m = m0 + r;
            const size_t base = (size_t)m*ND + bn*64;
            #pragma unroll
            for (int nt = 0; nt < 4; ++nt) {
                const size_t idx = base + nt*16 + l15;
                g_x[idx] = pack_bf2(Cr[nt][r] + Rr[idx], Ci[nt][r] + Ri[idx]);
            }
        }
    }
}

// ---------------- MFMA flash attention, chunk=32, KV-split x2, 4 blocks/CU ----------------
// R19 structure (best known): 2-buffer KV ring (LDS exactly 40KB), V fragments
// prefetched into registers before the coef lgkmcnt(0) drain. Q pre-scaled by
// log2e so softmax weight = exp2(mag + SHIFT) with a single add.
__global__ __launch_bounds__(256, 4)
void cattn()
{
    __shared__ __align__(16) short sKV[2][8192];              // [buf][Kr|Ki|Vr|Vi] 2048 shorts each
    __shared__ __align__(16) short sCr[64][32], sCi[64][32];  // coeffs [q][k32] (own-wave region)

    const int nb = blockIdx.x;
    const int xcd = nb & 7, rest = nb >> 3;        // rest 0..127
    const int bh = xcd*2 + (rest >> 6);
    const int within = rest & 63;
    const int q0 = (within >> 1) * 64;
    const int half = within & 1;

    const int tx = threadIdx.x;
    const int wave = tx >> 6, lane = tx & 63;
    const int l15 = lane & 15, l4 = lane >> 4;

    const short* Kr = g_bk_r + (size_t)bh*NL*NDK;
    const short* Ki = g_bk_i + (size_t)bh*NL*NDK;
    const short* Vr = g_bv_r + (size_t)bh*NL*NDK;
    const short* Vi = g_bv_i + (size_t)bh*NL*NDK;

    bf16x8 aQr[2], aQi[2], aQn[2];
    {
        const size_t qb = ((size_t)bh*NL + q0 + 16*wave + l15)*NDK + 8*l4;
        aQr[0] = *(const bf16x8*)(g_bq_r + qb);
        aQr[1] = *(const bf16x8*)(g_bq_r + qb + 32);
        aQi[0] = *(const bf16x8*)(g_bq_i + qb);
        aQi[1] = *(const bf16x8*)(g_bq_i + qb + 32);
        aQn[0] = negbf(aQi[0]); aQn[1] = negbf(aQi[1]);
    }

    f32x4 Or[4] = {}, Oi[4] = {};
    float ws[4] = {0.f, 0.f, 0.f, 0.f};

    const short* kvplane = (wave == 0) ? Kr : (wave == 1) ? Ki : (wave == 2) ? Vr : Vi;
    const int pbase = wave * 2048;

    #define STAGE_KV(CHUNK, BUF) do {                                         \
        _Pragma("unroll")                                                     \
        for (int i_ = 0; i_ < 4; ++i_) {                                      \
            const int u_ = i_*64 + lane;                                      \
            __builtin_amdgcn_global_load_lds(                                 \
                (const __attribute__((address_space(1))) void*)               \
                    (kvplane + (size_t)(CHUNK)*2048 + (size_t)u_*8),          \
                (__attribute__((address_space(3))) void*)                     \
                    &sKV[BUF][pbase + u_*8], 16, 0, 0);                       \
        }                                                                     \
    } while (0)

    const int cbase = half * 32;
    STAGE_KV(cbase, 0);
    asm volatile("s_waitcnt vmcnt(0)" ::: "memory");
    __syncthreads();

    const float SHIFT = -5.770780163f;     // -4 * log2(e); mag already in log2e units

    // V fragment LDS offsets (static per lane)
    int voff[4];
    #pragma unroll
    for (int tt = 0; tt < 4; ++tt) {
        const int r = (tt*16 + l15) & 31, dpart = tt >> 1;
        const int p = (4*dpart + l4) ^ (r & 7);
        voff[tt] = r*64 + p*8;
    }

    for (int t = 0; t < 32; ++t) {
        const int cur = t & 1, nxt = cur ^ 1;
        if (t < 31) STAGE_KV(cbase + t + 1, nxt);

        // ---- QK^T: 2 k-tiles of 16, coefficients emitted immediately ----
        #pragma unroll
        for (int tt = 0; tt < 2; ++tt) {
            const int row = tt*16 + l15;
            const int swb = row & 7;
            f32x4 Sr = {}, Si = {};
            __builtin_amdgcn_s_setprio(1);
            #pragma unroll
            for (int c = 0; c < 2; ++c) {
                const int off = (((c*4 + l4) ^ swb) << 3);
                const bf16x8 bKr = *(const bf16x8*)&sKV[cur][row*64 + off];
                const bf16x8 bKi = *(const bf16x8*)&sKV[cur][2048 + row*64 + off];
                Sr = __builtin_amdgcn_mfma_f32_16x16x32_bf16(aQr[c], bKr, Sr, 0, 0, 0);
                Sr = __builtin_amdgcn_mfma_f32_16x16x32_bf16(aQn[c], bKi, Sr, 0, 0, 0);
                Si = __builtin_amdgcn_mfma_f32_16x16x32_bf16(aQr[c], bKi, Si, 0, 0, 0);
                Si = __builtin_amdgcn_mfma_f32_16x16x32_bf16(aQi[c], bKr, Si, 0, 0, 0);
            }
            __builtin_amdgcn_s_setprio(0);
            const int kgrp = row >> 3;
            #pragma unroll
            for (int r = 0; r < 4; ++r) {
                const int qrow = 16*wave + 4*l4 + r;
                const float s2 = fmaxf(fmaf(Sr[r], Sr[r], Si[r]*Si[r]), 1e-30f);
                const float irs = __builtin_amdgcn_rsqf(s2);   // 1/|s|
                const float mag = s2 * irs;                    // |s| (log2e units)
                const float w = exp2f(mag + SHIFT);
                const float sc = w * irs;
                ws[r] += w;
                const int col = (row & 7) | ((kgrp ^ ((qrow >> 2) & 3)) << 3);
                const unsigned pk = pack_bf2(Sr[r]*sc, Si[r]*sc);
                sCr[qrow][col] = (short)(pk & 0xFFFFu);
                sCi[qrow][col] = (short)(pk >> 16);
            }
        }

        // ---- V prefetch (independent of coef exchange): issue before drain ----
        bf16x8 vfr0 = *(const bf16x8*)&sKV[cur][4096 + voff[0]];
        bf16x8 vfi0 = *(const bf16x8*)&sKV[cur][6144 + voff[0]];
        bf16x8 vfr1 = *(const bf16x8*)&sKV[cur][4096 + voff[1]];
        bf16x8 vfi1 = *(const bf16x8*)&sKV[cur][6144 + voff[1]];
        bf16x8 vfr2 = *(const bf16x8*)&sKV[cur][4096 + voff[2]];
        bf16x8 vfi2 = *(const bf16x8*)&sKV[cur][6144 + voff[2]];
        bf16x8 vfr3 = *(const bf16x8*)&sKV[cur][4096 + voff[3]];
        bf16x8 vfi3 = *(const bf16x8*)&sKV[cur][6144 + voff[3]];

        // drain: coef writes complete (wave-local region), V reads land.
        asm volatile("s_waitcnt lgkmcnt(0)" ::: "memory");
        __builtin_amdgcn_sched_barrier(0);

        // ---- PV: coef A-frag from LDS, V already in registers ----
        bf16x8 aCr, aCi, aCn;
        {
            const int qrow = 16*wave + l15;
            const int off = (l4 ^ ((qrow >> 2) & 3)) << 3;
            aCr = *(const bf16x8*)&sCr[qrow][off];
            aCi = *(const bf16x8*)&sCi[qrow][off];
            aCn = negbf(aCi);
        }
        __builtin_amdgcn_s_setprio(1);
        Or[0] = __builtin_amdgcn_mfma_f32_16x16x32_bf16(aCr, vfr0, Or[0], 0, 0, 0);
        Or[0] = __builtin_amdgcn_mfma_f32_16x16x32_bf16(aCn, vfi0, Or[0], 0, 0, 0);
        Oi[0] = __builtin_amdgcn_mfma_f32_16x16x32_bf16(aCr, vfi0, Oi[0], 0, 0, 0);
        Oi[0] = __builtin_amdgcn_mfma_f32_16x16x32_bf16(aCi, vfr0, Oi[0], 0, 0, 0);
        Or[1] = __builtin_amdgcn_mfma_f32_16x16x32_bf16(aCr, vfr1, Or[1], 0, 0, 0);
        Or[1] = __builtin_amdgcn_mfma_f32_16x16x32_bf16(aCn, vfi1, Or[1], 0, 0, 0);
        Oi[1] = __builtin_amdgcn_mfma_f32_16x16x32_bf16(aCr, vfi1, Oi[1], 0, 0, 0);
        Oi[1] = __builtin_amdgcn_mfma_f32_16x16x32_bf16(aCi, vfr1, Oi[1], 0, 0, 0);
        Or[2] = __builtin_amdgcn_mfma_f32_16x16x32_bf16(aCr, vfr2, Or[2], 0, 0, 0);
        Or[2] = __builtin_amdgcn_mfma_f32_16x16x32_bf16(aCn, vfi2, Or[2], 0, 0, 0);
        Oi[2] = __builtin_amdgcn_mfma_f32_16x16x32_bf16(aCr, vfi2, Oi[2], 0, 0, 0);
        Oi[2] = __builtin_amdgcn_mfma_f32_16x16x32_bf16(aCi, vfr2, Oi[2], 0, 0, 0);
        Or[3] = __builtin_amdgcn_mfma_f32_16x16x32_bf16(aCr, vfr3, Or[3], 0, 0, 0);
        Or[3] = __builtin_amdgcn_mfma_f32_16x16x32_bf16(aCn, vfi3, Or[3], 0, 0, 0);
        Oi[3] = __builtin_amdgcn_mfma_f32_16x16x32_bf16(aCr, vfi3, Oi[3], 0, 0, 0);
        Oi[3] = __builtin_amdgcn_mfma_f32_16x16x32_bf16(aCi, vfr3, Oi[3], 0, 0, 0);
        __builtin_amdgcn_s_setprio(0);

        asm volatile("s_waitcnt vmcnt(0)" ::: "memory");   // my KV-DMA done
        __syncthreads();                                    // everyone's DMA done
    }

    // ---- epilogue: reduce ws over 16-lane group; write packed bf16 partials ----
    #pragma unroll
    for (int r = 0; r < 4; ++r) {
        #pragma unroll
        for (int off = 8; off; off >>= 1) ws[r] += __shfl_xor(ws[r], off);
    }
    const size_t pb = (size_t)(half*16 + bh)*NL;
    if (l15 == 0) {
        #pragma unroll
        for (int r = 0; r < 4; ++r)
            g_pw[pb + q0 + 16*wave + 4*l4 + r] = ws[r];
    }
    #pragma unroll
    for (int tt = 0; tt < 4; ++tt) {
        const int d = tt*16 + l15;
        #pragma unroll
        for (int r = 0; r < 4; ++r) {
            const int q = q0 + 16*wave + 4*l4 + r;
            g_po[(pb + q)*NDK + d] = pack_bf2(Or[tt][r], Oi[tt][r]);
        }
    }
    #undef STAGE_KV
}

// ---------------- combine halves, normalize, emit bf16 PRE-SWIZZLED ----------------
__global__ __launch_bounds__(256)
void comb()
{
    const size_t t4 = ((size_t)blockIdx.x*256 + threadIdx.x) * 4;  // 2^21 elems total
    const int d = (int)(t4 & 63);
    const int q = (int)((t4 >> 6) & (NL-1));
    const int bh = (int)(t4 >> 17);
    const size_t p = ((size_t)bh*NL + q)*NDK + d;
    const uint4 a = *(const uint4*)&g_po[p];
    const uint4 c = *(const uint4*)&g_po[(size_t)16*NL*NDK + p];
    const float w = g_pw[(size_t)bh*NL + q] + g_pw[(size_t)(16 + bh)*NL + q];
    const float inv = 1.0f / w;
    float fr[4], fi[4];
    fr[0] = (bf_lo(a.x) + bf_lo(c.x))*inv; fi[0] = (bf_hi(a.x) + bf_hi(c.x))*inv;
    fr[1] = (bf_lo(a.y) + bf_lo(c.y))*inv; fi[1] = (bf_hi(a.y) + bf_hi(c.y))*inv;
    fr[2] = (bf_lo(a.z) + bf_lo(c.z))*inv; fi[2] = (bf_hi(a.z) + bf_hi(c.z))*inv;
    fr[3] = (bf_lo(a.w) + bf_lo(c.w))*inv; fi[3] = (bf_hi(a.w) + bf_hi(c.w))*inv;
    const int b = bh >> 3, h = bh & 7;
    const int dsw = ((((d >> 3) ^ (q & 7))) << 3) | (d & 7);   // pre-swizzle group
    const size_t o = ((size_t)b*NL + q)*ND + h*NDK + dsw;
    *(uint2*)(g_bo_r + o) = make_uint2(pack_bf2(fr[0], fr[1]), pack_bf2(fr[2], fr[3]));
    *(uint2*)(g_bo_i + o) = make_uint2(pack_bf2(fi[0], fi[1]), pack_bf2(fi[2], fi[3]));
}

// ---------------- covariance-whitening complex LayerNorm (packed g_x) ----------------
__global__ __launch_bounds__(256)
void cvln(const float* __restrict__ ln_w, const float* __restrict__ lnb_r,
          const float* __restrict__ lnb_i, float2* __restrict__ out)
{
    __shared__ float red[4][5];
    const int row = blockIdx.x, tx = threadIdx.x;
    const unsigned* xp = g_x + (size_t)row*ND;
    const unsigned u0 = xp[tx], u1 = xp[tx + 256];
    const float a0 = bf_lo(u0), a1 = bf_lo(u1);
    const float b0 = bf_hi(u0), b1 = bf_hi(u1);
    float s_r = a0 + a1, s_i = b0 + b1;
    float srr = a0*a0 + a1*a1, sii = b0*b0 + b1*b1, sri = a0*b0 + a1*b1;
    #pragma unroll
    for (int off = 32; off; off >>= 1) {
        s_r += __shfl_xor(s_r, off);  s_i += __shfl_xor(s_i, off);
        srr += __shfl_xor(srr, off);  sii += __shfl_xor(sii, off);
        sri += __shfl_xor(sri, off);
    }
    const int wave = tx >> 6, lane = tx & 63;
    if (lane == 0) { red[wave][0]=s_r; red[wave][1]=s_i; red[wave][2]=srr; red[wave][3]=sii; red[wave][4]=sri; }
    __syncthreads();
    s_r = red[0][0]+red[1][0]+red[2][0]+red[3][0];
    s_i = red[0][1]+red[1][1]+red[2][1]+red[3][1];
    srr = red[0][2]+red[1][2]+red[2][2]+red[3][2];
    sii = red[0][3]+red[1][3]+red[2][3]+red[3][3];
    sri = red[0][4]+red[1][4]+red[2][4]+red[3][4];

    const float invD = 1.0f/ND;
    const float mr = s_r*invD, mi = s_i*invD;
    const float vrr = srr*invD - mr*mr + 1e-6f;
    const float vii = sii*invD - mi*mi + 1e-6f;
    const float vri = sri*invD - mr*mi;
    const float s  = sqrtf(vrr*vii - vri*vri);
    const float t  = sqrtf(vrr + vii + 2.0f*s);
    const float inv = 1.0f/(s*t);
    const float rrr = (vii + s)*inv, rii = (vrr + s)*inv, rri = -vri*inv;

    #pragma unroll
    for (int p = 0; p < 2; ++p) {
        const int d = tx + p*256;
        const float cxr = (p ? a1 : a0) - mr;
        const float cxi = (p ? b1 : b0) - mi;
        const float yr = rrr*cxr + rri*cxi;
        const float yi = rri*cxr + rii*cxi;
        const float w00 = ln_w[d], w01 = ln_w[512 + d];
        const float w10 = ln_w[1024 + d], w11 = ln_w[1536 + d];
        out[(size_t)row*ND + d] = make_float2(w00*yr + w01*yi + lnb_r[d],
                                              w10*yr + w11*yi + lnb_i[d]);
    }
}

extern "C" void kernel_launch(void* const* d_in, const int* in_sizes, int n_in,
                              void* d_out, int out_size, void* d_ws, size_t ws_size,
                              hipStream_t stream)
{
    (void)in_sizes; (void)n_in; (void)d_ws; (void)ws_size; (void)out_size;
    const float* ln_w = (const float*)d_in[14];
    const float* lnbr = (const float*)d_in[15];
    const float* lnbi = (const float*)d_in[16];

    GPtrs gp;
    gp.xr[0] = (const float*)d_in[0];  gp.xi[0] = (const float*)d_in[1];
    gp.xr[1] = (const float*)d_in[2];  gp.xi[1] = (const float*)d_in[3];
    gp.xr[2] = (const float*)d_in[4];  gp.xi[2] = (const float*)d_in[5];
    gp.rr = (const float*)d_in[0];     gp.ri = (const float*)d_in[1];

    WPtrs wp;
    for (int j = 0; j < 8; ++j) wp.p[j] = (const float*)d_in[6 + j];

    const int wcvt_blocks = (int)((TOT_W/8 + 255)/256);
    tobf<<<wcvt_blocks, 256, 0, stream>>>(wp);
    bgemm<0><<<dim3(NROW/64, ND/64, 3), 256, 0, stream>>>(gp);
    cattn<<<1024, 256, 0, stream>>>();
    comb<<<2048, 256, 0, stream>>>();
    bgemm<1><<<dim3(NROW/64, ND/64), 256, 0, stream>>>(gp);
    cvln<<<NROW, 256, 0, stream>>>(ln_w, lnbr, lnbi, (float2*)d_out);
}